// Round 3
// baseline (3067.431 us; speedup 1.0000x reference)
//
#include <hip/hip_runtime.h>

#define T_STEPS 101
#define BATCH   16384
#define IN_DIM  40
#define HID     300
#define OUT_DIM 12

#define RPW 4             // rows per wave: amortizes W1 LDS reads 4x; walk MLP = 20
#define WPB 8             // waves per block (512 threads)
#define RPB (RPW * WPB)   // 32 rows per block
#define NTHREADS (WPB * 64)

typedef float f4 __attribute__((ext_vector_type(4)));

// ---- ws layout (floats) ----
// [0, 96000)         WhT[i][j] = Wh[j][i], column stride 320 (j in [300,320) = 0)
// [96000, 192000)    W2T[i][j] = W2[j][i], column stride 320
// [192000, 195600)   W3T[i][o] = W3[o][i], stride 12
#define WS_W2T 96000
#define WS_W3T 192000

// compile-time unroll helper: guarantees constexpr indices even when the
// loop body contains data-dependent while-loops (plain #pragma unroll bails
// -> dynamic alloca -> scratch traffic).
template<int I> struct ic { static constexpr int v = I; };
template<int N, int I = 0, typename F>
__device__ __forceinline__ void sfor(F&& f) {
    if constexpr (I < N) {
        f(ic<I>{});
        sfor<N, I + 1, F>(static_cast<F&&>(f));
    }
}

__global__ __launch_bounds__(256) void prep_kernel(const float* __restrict__ Wh,
                                                   const float* __restrict__ W2,
                                                   const float* __restrict__ W3,
                                                   float* __restrict__ ws) {
    int idx = blockIdx.x * 256 + threadIdx.x;
    if (idx < 96000) {
        int i = idx / 320, j = idx % 320;
        ws[idx] = (j < HID) ? Wh[j * HID + i] : 0.f;
    } else if (idx < 192000) {
        int k = idx - 96000;
        int i = k / 320, j = k % 320;
        ws[idx] = (j < HID) ? W2[j * HID + i] : 0.f;
    } else if (idx < 195600) {
        int k = idx - 192000;
        int i = k / OUT_DIM, j = k % OUT_DIM;
        ws[idx] = W3[j * HID + i];
    }
}

// Four-row interleaved sparse-column gather.
// FP-exactness contract: for each row, columns are added in ascending j order
// (same as the dense ascending dot, so skipped zero terms change nothing).
// fmaf(1.0f, w, a) rounds identically to a + w; rows whose mask is exhausted
// use g = 0.0f with a clamped (finite, in-range) dummy column -> a unchanged.
// Masks are wave-uniform (__ballot) -> SALU control flow; 20 loads issue
// before any wait -> MLP 20; chain length per u2-chunk = max(n0..n3).
__device__ __forceinline__ void walk4(const float* __restrict__ base, // tab + u2*64*320 + lane
                                      unsigned long long m0, unsigned long long m1,
                                      unsigned long long m2, unsigned long long m3,
                                      float (&a0)[5], float (&a1)[5],
                                      float (&a2)[5], float (&a3)[5]) {
    while (m0 | m1 | m2 | m3) {
        const bool h0 = (m0 != 0ull), h1 = (m1 != 0ull), h2 = (m2 != 0ull), h3 = (m3 != 0ull);
        const int b0 = h0 ? (int)__builtin_ctzll(m0) : 0;
        const int b1 = h1 ? (int)__builtin_ctzll(m1) : 0;
        const int b2 = h2 ? (int)__builtin_ctzll(m2) : 0;
        const int b3 = h3 ? (int)__builtin_ctzll(m3) : 0;
        m0 &= m0 - 1; m1 &= m1 - 1; m2 &= m2 - 1; m3 &= m3 - 1;   // 0-safe
        const float g0 = h0 ? 1.0f : 0.0f;
        const float g1 = h1 ? 1.0f : 0.0f;
        const float g2 = h2 ? 1.0f : 0.0f;
        const float g3 = h3 ? 1.0f : 0.0f;
        const float* p0 = base + b0 * 320;
        const float* p1 = base + b1 * 320;
        const float* p2 = base + b2 * 320;
        const float* p3 = base + b3 * 320;
        float l0[5], l1[5], l2[5], l3[5];
        sfor<5>([&](auto uc) { constexpr int u = decltype(uc)::v; l0[u] = p0[64 * u]; });
        sfor<5>([&](auto uc) { constexpr int u = decltype(uc)::v; l1[u] = p1[64 * u]; });
        sfor<5>([&](auto uc) { constexpr int u = decltype(uc)::v; l2[u] = p2[64 * u]; });
        sfor<5>([&](auto uc) { constexpr int u = decltype(uc)::v; l3[u] = p3[64 * u]; });
        sfor<5>([&](auto uc) { constexpr int u = decltype(uc)::v; a0[u] = fmaf(g0, l0[u], a0[u]); });
        sfor<5>([&](auto uc) { constexpr int u = decltype(uc)::v; a1[u] = fmaf(g1, l1[u], a1[u]); });
        sfor<5>([&](auto uc) { constexpr int u = decltype(uc)::v; a2[u] = fmaf(g2, l2[u], a2[u]); });
        sfor<5>([&](auto uc) { constexpr int u = decltype(uc)::v; a3[u] = fmaf(g3, l3[u], a3[u]); });
    }
}

// __launch_bounds__(512, 2): round-1 lesson — (512,4) forced a 64-VGPR cap and
// a 25 GB spill storm. (512,2) measured VGPR=128, no storm. Keep it.
__global__ __launch_bounds__(NTHREADS, 2) void snn_kernel(
    const float* __restrict__ x,    // [T, B, 40]
    const float* __restrict__ W1,   // [300, 40]
    const float* __restrict__ b1,   // [300]
    const float* __restrict__ bh,   // [300]
    const float* __restrict__ b2,   // [300]
    const float* __restrict__ b3,   // [12]
    const float* __restrict__ ws,   // transposed/padded weights
    float* __restrict__ out)        // [B, 12]
{
    // w1c[kc][j][c] = W1[j][4*kc+c], j padded to 320 (zeros). Lane reads
    // float4 at (kc*320 + j)*4 -> 16B stride across lanes: conflict-free.
    __shared__ float w1c[10 * 320 * 4];                 // 51200 B
    __shared__ float oacc[RPB][OUT_DIM];
    // Wave-private double-buffered x tile: xs[wave][buf][row][kc] (f4 chunks).
    // Round-2 post-mortem: streaming x through L2 evicted the 768 KB gather
    // tables -> 8 GB of HBM re-fetch on the serialized spike walks. x now
    // arrives via nontemporal loads (L2 streaming hint) prefetched one full
    // step ahead; tables stay L2-resident. Wave-private -> no __syncthreads.
    __shared__ f4 xs[WPB][2][RPW][10];                  // 10240 B

    const int tid  = threadIdx.x;
    const int lane = tid & 63;
    const int wv   = __builtin_amdgcn_readfirstlane(tid >> 6);  // wave-uniform
    const int row0 = blockIdx.x * RPB;

    // ---- stage W1 into chunked LDS layout ----
    for (int idx = tid; idx < 3200; idx += NTHREADS) {
        int kc = idx % 10;
        int j  = idx / 10;
        float4 v;
        if (j < HID) v = *(const float4*)(W1 + j * IN_DIM + kc * 4);
        else         v = make_float4(0.f, 0.f, 0.f, 0.f);
        *(float4*)(w1c + (kc * 320 + j) * 4) = v;
    }
    for (int idx = tid; idx < RPB * OUT_DIM; idx += NTHREADS) ((float*)oacc)[idx] = 0.f;

    // x staging lane map: lanes 0..39 each own one (row, kc) float4 chunk.
    const int lr_r = lane / 10;          // only meaningful for lane < 40
    const int lkc  = lane - lr_r * 10;
    const float* xbase = x + (size_t)(row0 + wv * RPW + lr_r) * IN_DIM + lkc * 4;

    // prologue: stage x(t=0) into buffer 0 (wave-private ordering only)
    {
        f4 nx0 = {0.f, 0.f, 0.f, 0.f};
        if (lane < 40) nx0 = __builtin_nontemporal_load((const f4*)xbase);
        if (lane < 40) xs[wv][0][lr_r][lkc] = nx0;
    }

    // per-lane biases for neurons j = lane + 64u (tail j>=300 -> 0)
    float b1h[5], b2r[5];
    sfor<5>([&](auto uc) {
        constexpr int u = decltype(uc)::v;
        int j = lane + 64 * u;
        b1h[u] = (j < HID) ? (b1[j] + bh[j]) : 0.f;
        b2r[u] = (j < HID) ? b2[j] : 0.f;
    });

    const float* WhT = ws;
    const float* W2T = ws + WS_W2T;
    const float* W3T = ws + WS_W3T;

    float v1[RPW][5], v2[RPW][5];
    // layer-1 spike masks: wave-uniform (__ballot) -> SGPRs. Written in Phase
    // C, read in Phase D (y @ W2^T) and next-t Phase B (y_{t-1} @ Wh^T).
    unsigned long long pm[RPW][5];
    sfor<RPW>([&](auto rc) {
        constexpr int r = decltype(rc)::v;
        sfor<5>([&](auto uc) {
            constexpr int u = decltype(uc)::v;
            v1[r][u] = 0.f; v2[r][u] = 0.f; pm[r][u] = 0ull;
        });
    });

    __syncthreads();

    const unsigned long long TAILMASK = (1ull << 44) - 1ull;  // 44 valid lanes at u=4

    for (int t = 0; t < T_STEPS; ++t) {
        const int cb = t & 1;

        // ---- prefetch x(t+1): issue nontemporal loads NOW, ds_write at step
        // end -> a full step of latency hiding. Clamped re-load at t=100 is
        // never read (avoids OOB without a divergent branch).
        f4 nx = {0.f, 0.f, 0.f, 0.f};
        {
            const int tn = (t + 1 < T_STEPS) ? t + 1 : t;
            if (lane < 40)
                nx = __builtin_nontemporal_load(
                        (const f4*)(xbase + (size_t)tn * (BATCH * IN_DIM)));
        }

        // ---- Phase A: h1 = x @ W1^T + (b1 + bh), x from LDS broadcast ----
        float acc[RPW][5];
        sfor<RPW>([&](auto rc) {
            constexpr int r = decltype(rc)::v;
            sfor<5>([&](auto uc) {
                constexpr int u = decltype(uc)::v;
                acc[r][u] = b1h[u];
            });
        });

        sfor<10>([&](auto kcc) {
            constexpr int kc = decltype(kcc)::v;
            f4 xq[RPW];
            sfor<RPW>([&](auto rc) {
                constexpr int r = decltype(rc)::v;
                xq[r] = xs[wv][cb][r][kc];      // uniform addr -> broadcast
            });
            // u outside r: w liveness 4 regs (was 20) to offset prefetch regs
            sfor<5>([&](auto uc) {
                constexpr int u = decltype(uc)::v;
                float4 w = *(const float4*)(w1c + (kc * 320 + lane + 64 * u) * 4);
                sfor<RPW>([&](auto rc) {
                    constexpr int r = decltype(rc)::v;
                    float a = acc[r][u];
                    a = fmaf(w.x, xq[r][0], a);
                    a = fmaf(w.y, xq[r][1], a);
                    a = fmaf(w.z, xq[r][2], a);
                    a = fmaf(w.w, xq[r][3], a);
                    acc[r][u] = a;
                });
            });
        });

        // ---- Phase B: recurrent input y_{t-1} @ Wh^T, 4 rows interleaved ----
        sfor<5>([&](auto u2c) {
            constexpr int u2 = decltype(u2c)::v;
            walk4(WhT + u2 * 64 * 320 + lane,
                  pm[0][u2], pm[1][u2], pm[2][u2], pm[3][u2],
                  acc[0], acc[1], acc[2], acc[3]);
        });

        // ---- Phase C: LIF layer 1 (v += (cur-v)/2 ; spike ; hard reset) ----
        sfor<RPW>([&](auto rc) {
            constexpr int r = decltype(rc)::v;
            sfor<5>([&](auto uc) {
                constexpr int u = decltype(uc)::v;
                float v = v1[r][u];
                v = v + (acc[r][u] - v) * 0.5f;
                bool s = (v >= 1.0f);
                v1[r][u] = s ? 0.f : v;
                pm[r][u] = __ballot(s);   // current y: used by D and next-t B
            });
            pm[r][4] &= TAILMASK;
        });

        // ---- Phase D: cur2 = y @ W2^T + b2, 4 rows interleaved ----
        float c2[RPW][5];
        sfor<RPW>([&](auto rc) {
            constexpr int r = decltype(rc)::v;
            sfor<5>([&](auto uc) {
                constexpr int u = decltype(uc)::v;
                c2[r][u] = b2r[u];
            });
        });
        sfor<5>([&](auto u2c) {
            constexpr int u2 = decltype(u2c)::v;
            walk4(W2T + u2 * 64 * 320 + lane,
                  pm[0][u2], pm[1][u2], pm[2][u2], pm[3][u2],
                  c2[0], c2[1], c2[2], c2[3]);
        });

        // ---- Phase E: LIF layer 2 + output accumulation (s2 spikes rare) ----
        sfor<RPW>([&](auto rc) {
            constexpr int r = decltype(rc)::v;
            unsigned long long sm[5];
            sfor<5>([&](auto uc) {
                constexpr int u = decltype(uc)::v;
                float v = v2[r][u];
                v = v + (c2[r][u] - v) * 0.5f;
                bool s = (v >= 1.0f);
                v2[r][u] = s ? 0.f : v;
                sm[u] = __ballot(s);
            });
            sm[4] &= TAILMASK;
            const int lr = wv * RPW + r;
            sfor<5>([&](auto u2c) {
                constexpr int u2 = decltype(u2c)::v;
                unsigned long long m = sm[u2];
                while (m) {
                    int b = __builtin_ctzll(m);
                    m &= m - 1;
                    if (lane < OUT_DIM)
                        oacc[lr][lane] += W3T[(u2 * 64 + b) * OUT_DIM + lane];
                }
            });
        });

        // ---- commit prefetched x(t+1) (wave-private; compiler orders ds ops)
        if (lane < 40) xs[wv][(t + 1) & 1][lr_r][lkc] = nx;
    }

    __syncthreads();

    // ---- epilogue: out = oacc + 101 * b3 ----
    for (int idx = tid; idx < RPB * OUT_DIM; idx += NTHREADS) {
        int r = idx / OUT_DIM, o = idx % OUT_DIM;
        out[(size_t)(row0 + r) * OUT_DIM + o] = oacc[r][o] + 101.0f * b3[o];
    }
}

extern "C" void kernel_launch(void* const* d_in, const int* in_sizes, int n_in,
                              void* d_out, int out_size, void* d_ws, size_t ws_size,
                              hipStream_t stream) {
    const float* x  = (const float*)d_in[0];
    const float* W1 = (const float*)d_in[1];
    const float* b1 = (const float*)d_in[2];
    const float* Wh = (const float*)d_in[3];
    const float* bh = (const float*)d_in[4];
    const float* W2 = (const float*)d_in[5];
    const float* b2 = (const float*)d_in[6];
    const float* W3 = (const float*)d_in[7];
    const float* b3 = (const float*)d_in[8];
    float* out = (float*)d_out;
    float* ws  = (float*)d_ws;

    prep_kernel<<<(195600 + 255) / 256, 256, 0, stream>>>(Wh, W2, W3, ws);
    snn_kernel<<<BATCH / RPB, NTHREADS, 0, stream>>>(x, W1, b1, bh, b2, b3, ws, out);
}

// Round 6
// 2746.302 us; speedup vs baseline: 1.1169x; 1.1169x over previous
//
#include <hip/hip_runtime.h>

#define T_STEPS 101
#define BATCH   16384
#define IN_DIM  40
#define HID     300
#define OUT_DIM 12

#define RPW 4             // rows per wave: amortizes W1 LDS reads 4x
#define WPB 8             // waves per block (512 threads)
#define RPB (RPW * WPB)   // 32 rows per block
#define NTHREADS (WPB * 64)

// ---- ws layout (floats) ----
// [0, 96000)         WhT[i][j] = Wh[j][i], column stride 320 (j in [300,320) = 0)
// [96000, 192000)    W2T[i][j] = W2[j][i], column stride 320
// [192000, 195600)   W3T[i][o] = W3[o][i], stride 12
#define WS_W2T 96000
#define WS_W3T 192000

// compile-time unroll helper: guarantees constexpr indices even when the
// loop body contains data-dependent while-loops (plain #pragma unroll bails
// -> dynamic alloca -> scratch traffic).
template<int I> struct ic { static constexpr int v = I; };
template<int N, int I = 0, typename F>
__device__ __forceinline__ void sfor(F&& f) {
    if constexpr (I < N) {
        f(ic<I>{});
        sfor<N, I + 1, F>(static_cast<F&&>(f));
    }
}

__global__ __launch_bounds__(256) void prep_kernel(const float* __restrict__ Wh,
                                                   const float* __restrict__ W2,
                                                   const float* __restrict__ W3,
                                                   float* __restrict__ ws) {
    int idx = blockIdx.x * 256 + threadIdx.x;
    if (idx < 96000) {
        int i = idx / 320, j = idx % 320;
        ws[idx] = (j < HID) ? Wh[j * HID + i] : 0.f;
    } else if (idx < 192000) {
        int k = idx - 96000;
        int i = k / 320, j = k % 320;
        ws[idx] = (j < HID) ? W2[j * HID + i] : 0.f;
    } else if (idx < 195600) {
        int k = idx - 192000;
        int i = k / OUT_DIM, j = k % OUT_DIM;
        ws[idx] = W3[j * HID + i];
    }
}

// Four-row, TWO-BITS-PER-ROW interleaved sparse-column gather.
// Round-3 post-mortem: the kernel is ~90% serialized memory waits, one per
// walk iteration (issue 20 loads -> waitcnt -> fma -> branch). Extracting two
// bits per row per iteration issues 40 loads before any use -> the number of
// serialized round-trips per chunk drops from max(n) to ceil(max(n)/2).
// FP-exactness contract: per (row,u) the REAL fma sequence stays ascending-
// bit-order; dummy fmaf(0, l, a) leaves a bit-identical (finite l; exact
// cancellation yields +0 in RN so acc is never -0), same trick walk4 already
// used and which measured absmax = 0.0.
__device__ __forceinline__ void walk4x2(const float* __restrict__ base, // tab + u2*64*320 + lane
                                        unsigned long long m0, unsigned long long m1,
                                        unsigned long long m2, unsigned long long m3,
                                        float (&a0)[5], float (&a1)[5],
                                        float (&a2)[5], float (&a3)[5]) {
    while (m0 | m1 | m2 | m3) {
        // extraction a (first bit of each row)
        const bool h0a = (m0 != 0ull), h1a = (m1 != 0ull), h2a = (m2 != 0ull), h3a = (m3 != 0ull);
        const int b0a = h0a ? (int)__builtin_ctzll(m0) : 0;
        const int b1a = h1a ? (int)__builtin_ctzll(m1) : 0;
        const int b2a = h2a ? (int)__builtin_ctzll(m2) : 0;
        const int b3a = h3a ? (int)__builtin_ctzll(m3) : 0;
        m0 &= m0 - 1; m1 &= m1 - 1; m2 &= m2 - 1; m3 &= m3 - 1;   // 0-safe
        // extraction b (second bit of each row)
        const bool h0b = (m0 != 0ull), h1b = (m1 != 0ull), h2b = (m2 != 0ull), h3b = (m3 != 0ull);
        const int b0b = h0b ? (int)__builtin_ctzll(m0) : 0;
        const int b1b = h1b ? (int)__builtin_ctzll(m1) : 0;
        const int b2b = h2b ? (int)__builtin_ctzll(m2) : 0;
        const int b3b = h3b ? (int)__builtin_ctzll(m3) : 0;
        m0 &= m0 - 1; m1 &= m1 - 1; m2 &= m2 - 1; m3 &= m3 - 1;

        const float g0a = h0a ? 1.0f : 0.0f, g1a = h1a ? 1.0f : 0.0f;
        const float g2a = h2a ? 1.0f : 0.0f, g3a = h3a ? 1.0f : 0.0f;
        const float g0b = h0b ? 1.0f : 0.0f, g1b = h1b ? 1.0f : 0.0f;
        const float g2b = h2b ? 1.0f : 0.0f, g3b = h3b ? 1.0f : 0.0f;

        const float* p0a = base + b0a * 320;
        const float* p1a = base + b1a * 320;
        const float* p2a = base + b2a * 320;
        const float* p3a = base + b3a * 320;
        const float* p0b = base + b0b * 320;
        const float* p1b = base + b1b * 320;
        const float* p2b = base + b2b * 320;
        const float* p3b = base + b3b * 320;

        float l0a[5], l1a[5], l2a[5], l3a[5], l0b[5], l1b[5], l2b[5], l3b[5];
        sfor<5>([&](auto uc) { constexpr int u = decltype(uc)::v; l0a[u] = p0a[64 * u]; });
        sfor<5>([&](auto uc) { constexpr int u = decltype(uc)::v; l1a[u] = p1a[64 * u]; });
        sfor<5>([&](auto uc) { constexpr int u = decltype(uc)::v; l2a[u] = p2a[64 * u]; });
        sfor<5>([&](auto uc) { constexpr int u = decltype(uc)::v; l3a[u] = p3a[64 * u]; });
        sfor<5>([&](auto uc) { constexpr int u = decltype(uc)::v; l0b[u] = p0b[64 * u]; });
        sfor<5>([&](auto uc) { constexpr int u = decltype(uc)::v; l1b[u] = p1b[64 * u]; });
        sfor<5>([&](auto uc) { constexpr int u = decltype(uc)::v; l2b[u] = p2b[64 * u]; });
        sfor<5>([&](auto uc) { constexpr int u = decltype(uc)::v; l3b[u] = p3b[64 * u]; });

        // apply a then b: ascending-bit order per row preserved
        sfor<5>([&](auto uc) { constexpr int u = decltype(uc)::v; a0[u] = fmaf(g0a, l0a[u], a0[u]); });
        sfor<5>([&](auto uc) { constexpr int u = decltype(uc)::v; a1[u] = fmaf(g1a, l1a[u], a1[u]); });
        sfor<5>([&](auto uc) { constexpr int u = decltype(uc)::v; a2[u] = fmaf(g2a, l2a[u], a2[u]); });
        sfor<5>([&](auto uc) { constexpr int u = decltype(uc)::v; a3[u] = fmaf(g3a, l3a[u], a3[u]); });
        sfor<5>([&](auto uc) { constexpr int u = decltype(uc)::v; a0[u] = fmaf(g0b, l0b[u], a0[u]); });
        sfor<5>([&](auto uc) { constexpr int u = decltype(uc)::v; a1[u] = fmaf(g1b, l1b[u], a1[u]); });
        sfor<5>([&](auto uc) { constexpr int u = decltype(uc)::v; a2[u] = fmaf(g2b, l2b[u], a2[u]); });
        sfor<5>([&](auto uc) { constexpr int u = decltype(uc)::v; a3[u] = fmaf(g3b, l3b[u], a3[u]); });
    }
}

// __launch_bounds__(512, 2): measured VGPR=128, no spill storm (round 2).
// Round-1 lesson: (512,4) forced a 64-VGPR cap -> 25 GB scratch traffic.
__global__ __launch_bounds__(NTHREADS, 2) void snn_kernel(
    const float* __restrict__ x,    // [T, B, 40]
    const float* __restrict__ W1,   // [300, 40]
    const float* __restrict__ b1,   // [300]
    const float* __restrict__ bh,   // [300]
    const float* __restrict__ b2,   // [300]
    const float* __restrict__ b3,   // [12]
    const float* __restrict__ ws,   // transposed/padded weights
    float* __restrict__ out)        // [B, 12]
{
    // w1c[kc][j][c] = W1[j][4*kc+c], j padded to 320 (zeros). Lane reads
    // float4 at (kc*320 + j)*4 -> 16B stride across lanes: conflict-free.
    __shared__ float w1c[10 * 320 * 4];                 // 51200 B
    __shared__ float oacc[RPB][OUT_DIM];
    // biases moved to LDS (was 10 persistent VGPRs): funds the x2-unroll's
    // +20 live load registers under the 128-VGPR cap. b1[j]+bh[j] computed
    // once in fp32 here -> bit-identical to the per-thread version.
    __shared__ float bl1[320], bl2[320];                // 2560 B

    const int tid  = threadIdx.x;
    const int lane = tid & 63;
    const int wv   = __builtin_amdgcn_readfirstlane(tid >> 6);  // wave-uniform
    const int row0 = blockIdx.x * RPB;

    // ---- stage W1 into chunked LDS layout ----
    for (int idx = tid; idx < 3200; idx += NTHREADS) {
        int kc = idx % 10;
        int j  = idx / 10;
        float4 v;
        if (j < HID) v = *(const float4*)(W1 + j * IN_DIM + kc * 4);
        else         v = make_float4(0.f, 0.f, 0.f, 0.f);
        *(float4*)(w1c + (kc * 320 + j) * 4) = v;
    }
    for (int idx = tid; idx < 320; idx += NTHREADS) {   // NTHREADS > 320: one pass
        bl1[idx] = (idx < HID) ? (b1[idx] + bh[idx]) : 0.f;
        bl2[idx] = (idx < HID) ? b2[idx] : 0.f;
    }
    for (int idx = tid; idx < RPB * OUT_DIM; idx += NTHREADS) ((float*)oacc)[idx] = 0.f;

    const float* WhT = ws;
    const float* W2T = ws + WS_W2T;
    const float* W3T = ws + WS_W3T;

    float v1[RPW][5], v2[RPW][5];
    // layer-1 spike masks: wave-uniform (__ballot) -> SGPRs. Written in Phase
    // C, read in Phase D (y @ W2^T) and next-t Phase B (y_{t-1} @ Wh^T).
    unsigned long long pm[RPW][5];
    sfor<RPW>([&](auto rc) {
        constexpr int r = decltype(rc)::v;
        sfor<5>([&](auto uc) {
            constexpr int u = decltype(uc)::v;
            v1[r][u] = 0.f; v2[r][u] = 0.f; pm[r][u] = 0ull;
        });
    });

    __syncthreads();

    const unsigned long long TAILMASK = (1ull << 44) - 1ull;  // 44 valid lanes at u=4

    for (int t = 0; t < T_STEPS; ++t) {
        // wave-uniform base for this wave's 4 rows at step t -> s_load path
        const float* xt = x + ((size_t)t * BATCH + row0 + wv * RPW) * IN_DIM;

        // ---- Phase A: h1 = x @ W1^T + (b1 + bh) ----
        float acc[RPW][5];
        {
            float bq[5];
            sfor<5>([&](auto uc) {
                constexpr int u = decltype(uc)::v;
                bq[u] = bl1[lane + 64 * u];
            });
            sfor<RPW>([&](auto rc) {
                constexpr int r = decltype(rc)::v;
                sfor<5>([&](auto uc) {
                    constexpr int u = decltype(uc)::v;
                    acc[r][u] = bq[u];
                });
            });
        }

        sfor<10>([&](auto kcc) {
            constexpr int kc = decltype(kcc)::v;
            float4 w[5];
            sfor<5>([&](auto uc) {
                constexpr int u = decltype(uc)::v;
                w[u] = *(const float4*)(w1c + (kc * 320 + lane + 64 * u) * 4);
            });
            sfor<RPW>([&](auto rc) {
                constexpr int r = decltype(rc)::v;
                const float* xr = xt + r * IN_DIM + kc * 4;   // uniform -> s_load
                float x0 = xr[0], x1 = xr[1], x2 = xr[2], x3 = xr[3];
                sfor<5>([&](auto uc) {
                    constexpr int u = decltype(uc)::v;
                    float a = acc[r][u];
                    a = fmaf(w[u].x, x0, a);
                    a = fmaf(w[u].y, x1, a);
                    a = fmaf(w[u].z, x2, a);
                    a = fmaf(w[u].w, x3, a);
                    acc[r][u] = a;
                });
            });
        });

        // ---- Phase B: recurrent input y_{t-1} @ Wh^T, 4 rows x 2 bits ----
        sfor<5>([&](auto u2c) {
            constexpr int u2 = decltype(u2c)::v;
            walk4x2(WhT + u2 * 64 * 320 + lane,
                    pm[0][u2], pm[1][u2], pm[2][u2], pm[3][u2],
                    acc[0], acc[1], acc[2], acc[3]);
        });

        // ---- Phase C: LIF layer 1 (v += (cur-v)/2 ; spike ; hard reset) ----
        sfor<RPW>([&](auto rc) {
            constexpr int r = decltype(rc)::v;
            sfor<5>([&](auto uc) {
                constexpr int u = decltype(uc)::v;
                float v = v1[r][u];
                v = v + (acc[r][u] - v) * 0.5f;
                bool s = (v >= 1.0f);
                v1[r][u] = s ? 0.f : v;
                pm[r][u] = __ballot(s);   // current y: used by D and next-t B
            });
            pm[r][4] &= TAILMASK;
        });

        // ---- Phase D: cur2 = y @ W2^T + b2, 4 rows x 2 bits ----
        float c2[RPW][5];
        {
            float bq[5];
            sfor<5>([&](auto uc) {
                constexpr int u = decltype(uc)::v;
                bq[u] = bl2[lane + 64 * u];
            });
            sfor<RPW>([&](auto rc) {
                constexpr int r = decltype(rc)::v;
                sfor<5>([&](auto uc) {
                    constexpr int u = decltype(uc)::v;
                    c2[r][u] = bq[u];
                });
            });
        }
        sfor<5>([&](auto u2c) {
            constexpr int u2 = decltype(u2c)::v;
            walk4x2(W2T + u2 * 64 * 320 + lane,
                    pm[0][u2], pm[1][u2], pm[2][u2], pm[3][u2],
                    c2[0], c2[1], c2[2], c2[3]);
        });

        // ---- Phase E: LIF layer 2 + output accumulation (s2 spikes rare) ----
        sfor<RPW>([&](auto rc) {
            constexpr int r = decltype(rc)::v;
            unsigned long long sm[5];
            sfor<5>([&](auto uc) {
                constexpr int u = decltype(uc)::v;
                float v = v2[r][u];
                v = v + (c2[r][u] - v) * 0.5f;
                bool s = (v >= 1.0f);
                v2[r][u] = s ? 0.f : v;
                sm[u] = __ballot(s);
            });
            sm[4] &= TAILMASK;
            const int lr = wv * RPW + r;
            sfor<5>([&](auto u2c) {
                constexpr int u2 = decltype(u2c)::v;
                unsigned long long m = sm[u2];
                while (m) {
                    int b = __builtin_ctzll(m);
                    m &= m - 1;
                    if (lane < OUT_DIM)
                        oacc[lr][lane] += W3T[(u2 * 64 + b) * OUT_DIM + lane];
                }
            });
        });
    }

    __syncthreads();

    // ---- epilogue: out = oacc + 101 * b3 ----
    for (int idx = tid; idx < RPB * OUT_DIM; idx += NTHREADS) {
        int r = idx / OUT_DIM, o = idx % OUT_DIM;
        out[(size_t)(row0 + r) * OUT_DIM + o] = oacc[r][o] + 101.0f * b3[o];
    }
}

extern "C" void kernel_launch(void* const* d_in, const int* in_sizes, int n_in,
                              void* d_out, int out_size, void* d_ws, size_t ws_size,
                              hipStream_t stream) {
    const float* x  = (const float*)d_in[0];
    const float* W1 = (const float*)d_in[1];
    const float* b1 = (const float*)d_in[2];
    const float* Wh = (const float*)d_in[3];
    const float* bh = (const float*)d_in[4];
    const float* W2 = (const float*)d_in[5];
    const float* b2 = (const float*)d_in[6];
    const float* W3 = (const float*)d_in[7];
    const float* b3 = (const float*)d_in[8];
    float* out = (float*)d_out;
    float* ws  = (float*)d_ws;

    prep_kernel<<<(195600 + 255) / 256, 256, 0, stream>>>(Wh, W2, W3, ws);
    snn_kernel<<<BATCH / RPB, NTHREADS, 0, stream>>>(x, W1, b1, bh, b2, b3, ws, out);
}